// Round 3
// baseline (117.650 us; speedup 1.0000x reference)
//
#include <hip/hip_runtime.h>

#define HW    (768*768)
#define N4    (HW/4)        // 147456 float4 groups per plane per image
#define MAXI  33
#define NBINS (4*MAXI)      // [0..32]=count, [33..65]=sin, [66..98]=cos, [99..131]=r
#define B_IMG 8
#define NTHR  256
#define GX    288           // blocks per image; GX*NTHR*NJ == N4 exactly
#define NJ    2

// -------- Single fused pass: per-id bins (count + 3 weighted-error sums) --------
// loss = sum_id f(id) * S_id ; f(id) = 1/max(cnt,1) * (id>0 ? 1/n_inst : 1)
__global__ __launch_bounds__(NTHR, 8) void main_pass(
    const float* __restrict__ pred, const int* __restrict__ inst,
    const float* __restrict__ gtR,  const float* __restrict__ gts,
    const float* __restrict__ gtc,  const float* __restrict__ gci,
    const int* __restrict__ ign,
    float* __restrict__ g_bins)
{
    const int b = blockIdx.y;
    __shared__ float bins[NBINS];
    for (int t = threadIdx.x; t < NBINS; t += NTHR) bins[t] = 0.f;
    __syncthreads();

    const size_t off = (size_t)b * HW;
    const int4*   ip  = (const int4*)(inst + off);
    const int4*   gp  = (const int4*)(ign  + off);
    const float4* Rp  = (const float4*)(gtR + off);
    const float4* sp  = (const float4*)(gts + off);
    const float4* cp  = (const float4*)(gtc + off);
    const float4* cip = (const float4*)(gci + off);
    const float4* p0  = (const float4*)(pred + ((size_t)b*3+0)*HW);
    const float4* p1  = (const float4*)(pred + ((size_t)b*3+1)*HW);
    const float4* p2  = (const float4*)(pred + ((size_t)b*3+2)*HW);

    // each block owns a contiguous range of NJ*NTHR groups
    const int base = blockIdx.x * (NJ * NTHR) + threadIdx.x;

    // branchless per-pixel: cnt = (g==0), w = (g==0)*ci; all lanes always atomic.
    auto PIX = [&](int id, int gg, float ci, float gs, float gc, float R,
                   float ps, float pc, float pr) {
        const float v = (gg == 0) ? 1.0f : 0.0f;
        const float w = v * ci;
        atomicAdd(&bins[id],      v);
        atomicAdd(&bins[33 + id], w * fabsf(ps - gs));
        atomicAdd(&bins[66 + id], w * fabsf(pc - gc));
        atomicAdd(&bins[99 + id], w * fabsf(pr - __logf(R + 1.f)));
    };

    #pragma unroll
    for (int j = 0; j < NJ; ++j) {
        const int i = base + j * NTHR;
        int4   id4 = ip[i];
        int4   g4  = gp[i];
        float4 ci  = cip[i];
        float4 si  = sp[i];
        float4 co  = cp[i];
        float4 R   = Rp[i];
        float4 a   = p0[i];
        float4 bb  = p1[i];
        float4 rr  = p2[i];

        PIX(id4.x, g4.x, ci.x, si.x, co.x, R.x, a.x, bb.x, rr.x);
        PIX(id4.y, g4.y, ci.y, si.y, co.y, R.y, a.y, bb.y, rr.y);
        PIX(id4.z, g4.z, ci.z, si.z, co.z, R.z, a.z, bb.z, rr.z);
        PIX(id4.w, g4.w, ci.w, si.w, co.w, R.w, a.w, bb.w, rr.w);
    }

    __syncthreads();
    if (threadIdx.x < NBINS)
        atomicAdd(&g_bins[b * NBINS + threadIdx.x], bins[threadIdx.x]);
}

// -------- Finalize: apply per-id weighting, write all 64 outputs --------
__global__ __launch_bounds__(NTHR) void finalize(
    const float* __restrict__ g_bins, float* __restrict__ out)
{
    const int b = blockIdx.x;
    __shared__ float red[NBINS];
    if (threadIdx.x < NBINS) red[threadIdx.x] = g_bins[b * NBINS + threadIdx.x];
    __syncthreads();
    if (threadIdx.x == 0) {
        float n = 0.f;
        for (int id = 1; id < MAXI; ++id) n += (red[id] > 0.f) ? 1.f : 0.f;
        n = fmaxf(n, 1.f);
        float ts = 0.f, tc = 0.f, tr = 0.f;
        for (int id = 0; id < MAXI; ++id) {
            float f = 1.f / fmaxf(red[id], 1.f);
            if (id > 0) f *= 1.f / n;
            ts += f * red[33 + id];
            tc += f * red[66 + id];
            tr += f * red[99 + id];
        }
        float tot = ts + tc + tr;
        out[     b] = tot;
        out[ 8 + b] = 0.f;
        out[16 + b] = tot;
        out[24 + b] = 0.f;
        out[32 + b] = ts;
        out[40 + b] = tc;
        out[48 + b] = tr;
        out[56 + b] = 0.f;
    }
}

extern "C" void kernel_launch(void* const* d_in, const int* in_sizes, int n_in,
                              void* d_out, int out_size, void* d_ws, size_t ws_size,
                              hipStream_t stream) {
    const float* pred = (const float*)d_in[0];
    const int*   inst = (const int*)d_in[1];
    // d_in[2] = label (unused by the reference)
    const float* gtR  = (const float*)d_in[3];
    const float* gts  = (const float*)d_in[4];
    const float* gtc  = (const float*)d_in[5];
    const float* gci  = (const float*)d_in[6];
    const int*   ign  = (const int*)d_in[7];
    float* out    = (float*)d_out;
    float* g_bins = (float*)d_ws;

    hipMemsetAsync(g_bins, 0, B_IMG * NBINS * sizeof(float), stream);

    dim3 grid(GX, B_IMG);
    main_pass<<<grid, NTHR, 0, stream>>>(pred, inst, gtR, gts, gtc, gci, ign, g_bins);
    finalize<<<B_IMG, NTHR, 0, stream>>>(g_bins, out);
}

// Round 4
// 51.859 us; speedup vs baseline: 2.2686x; 2.2686x over previous
//
#include <hip/hip_runtime.h>

#define HW     (768*768)      // 589824 pixels per plane
#define N4     (HW/4)         // 147456 float4/int4 groups
#define MAXI   33
#define B_IMG  8
#define NTHR   256
#define GXB    192            // blocks per image: GXB*NTHR*NJ == N4 exactly
#define NJ     3
#define GPB    (NTHR*NJ)      // 768 groups per block

// ---------- Pass 1: ballot-histogram of valid-pixel ids + fused widx byte plane ----------
// vid = valid ? id : 33.  Count for bin k accumulates in lane k's register via
// popcll(ballot(vid==k)) — no atomics in the hot loop.
__global__ __launch_bounds__(NTHR, 8) void pass1_count(
    const int* __restrict__ inst, const int* __restrict__ ign,
    int* __restrict__ g_counts, uchar4* __restrict__ wbp, int write_bytes)
{
    const int b = blockIdx.y;
    const size_t goff = (size_t)b * N4;
    const int4* ip = (const int4*)inst + goff;
    const int4* gp = (const int4*)ign  + goff;
    uchar4* wp = wbp + goff;
    const int base = blockIdx.x * GPB + threadIdx.x;
    const int lane = threadIdx.x & 63;
    const int wv   = threadIdx.x >> 6;

    int acc = 0;                       // count for bin == lane (lanes 0..32)
    #pragma unroll
    for (int j = 0; j < NJ; ++j) {
        const int i = base + j * NTHR;
        int4 id4 = ip[i];
        int4 g4  = gp[i];
        int v0 = (g4.x == 0) ? id4.x : MAXI;
        int v1 = (g4.y == 0) ? id4.y : MAXI;
        int v2 = (g4.z == 0) ? id4.z : MAXI;
        int v3 = (g4.w == 0) ? id4.w : MAXI;
        if (write_bytes)
            wp[i] = make_uchar4((unsigned char)v0, (unsigned char)v1,
                                (unsigned char)v2, (unsigned char)v3);
        for (int k = 0; k < MAXI; ++k) {
            int c = __popcll(__ballot(v0 == k)) + __popcll(__ballot(v1 == k))
                  + __popcll(__ballot(v2 == k)) + __popcll(__ballot(v3 == k));
            acc += (lane == k) ? c : 0;
        }
    }
    __shared__ int s_cnt[NTHR / 64][MAXI];
    if (lane < MAXI) s_cnt[wv][lane] = acc;
    __syncthreads();
    if (threadIdx.x < MAXI) {
        int t = 0;
        #pragma unroll
        for (int w = 0; w < NTHR / 64; ++w) t += s_cnt[w][threadIdx.x];
        atomicAdd(&g_counts[b * MAXI + threadIdx.x], t);   // 33 int atomics per block
    }
}

// ---------- Pass 2: weighted L1 accumulate, LDS weight LUT, register accumulation ----------
template<int SRC>   // 1 = read byte plane, 0 = read raw inst+ign
__global__ __launch_bounds__(NTHR, 6) void pass2_loss(
    const float* __restrict__ pred,
    const int* __restrict__ inst, const int* __restrict__ ign,
    const uchar4* __restrict__ wbp,
    const float* __restrict__ gtR, const float* __restrict__ gts,
    const float* __restrict__ gtc, const float* __restrict__ gci,
    const int* __restrict__ g_counts, float* __restrict__ partials)
{
    const int b = blockIdx.y;
    __shared__ float lut[MAXI + 1];
    __shared__ float s_ninv;
    if (threadIdx.x == 0) {
        int n = 0;
        for (int k = 1; k < MAXI; ++k) n += (g_counts[b * MAXI + k] > 0) ? 1 : 0;
        s_ninv = 1.0f / fmaxf((float)n, 1.0f);
    }
    __syncthreads();
    if (threadIdx.x < MAXI) {
        float sz = fmaxf((float)g_counts[b * MAXI + threadIdx.x], 1.0f);
        float f = 1.0f / sz;
        if (threadIdx.x > 0) f *= s_ninv;
        lut[threadIdx.x] = f;
    }
    if (threadIdx.x == MAXI) lut[MAXI] = 0.0f;   // invalid pixels -> weight 0
    __syncthreads();

    const size_t goff = (size_t)b * N4;
    const float4* p0  = (const float4*)pred + (size_t)(b * 3 + 0) * N4;
    const float4* p1  = (const float4*)pred + (size_t)(b * 3 + 1) * N4;
    const float4* p2  = (const float4*)pred + (size_t)(b * 3 + 2) * N4;
    const float4* Rp  = (const float4*)gtR + goff;
    const float4* sp  = (const float4*)gts + goff;
    const float4* cp  = (const float4*)gtc + goff;
    const float4* cip = (const float4*)gci + goff;
    const uchar4* wp  = wbp + goff;
    const int4*   ipp = (const int4*)inst + goff;
    const int4*   gpp = (const int4*)ign  + goff;

    const int base = blockIdx.x * GPB + threadIdx.x;
    float as = 0.f, ac = 0.f, ar = 0.f;

#define LOADG(J, S) \
    const int i##S = base + (J) * NTHR; \
    float4 a##S  = p0[i##S]; float4 bb##S = p1[i##S]; float4 rr##S = p2[i##S]; \
    float4 R##S  = Rp[i##S]; float4 si##S = sp[i##S]; float4 co##S = cp[i##S]; \
    float4 ci##S = cip[i##S]; \
    int w0##S, w1##S, w2##S, w3##S; \
    if constexpr (SRC) { \
        uchar4 u = wp[i##S]; w0##S = u.x; w1##S = u.y; w2##S = u.z; w3##S = u.w; \
    } else { \
        int4 id4 = ipp[i##S]; int4 g4 = gpp[i##S]; \
        w0##S = (g4.x == 0) ? id4.x : MAXI; w1##S = (g4.y == 0) ? id4.y : MAXI; \
        w2##S = (g4.z == 0) ? id4.z : MAXI; w3##S = (g4.w == 0) ? id4.w : MAXI; \
    }

#define PIX1(wv_, cc, gs, gc, Rv, ps, pc, pr) { \
    float w = lut[wv_] * (cc); \
    as += w * fabsf((ps) - (gs)); \
    ac += w * fabsf((pc) - (gc)); \
    ar += w * fabsf((pr) - __logf((Rv) + 1.f)); }

#define PROC(S) \
    PIX1(w0##S, ci##S.x, si##S.x, co##S.x, R##S.x, a##S.x, bb##S.x, rr##S.x); \
    PIX1(w1##S, ci##S.y, si##S.y, co##S.y, R##S.y, a##S.y, bb##S.y, rr##S.y); \
    PIX1(w2##S, ci##S.z, si##S.z, co##S.z, R##S.z, a##S.z, bb##S.z, rr##S.z); \
    PIX1(w3##S, ci##S.w, si##S.w, co##S.w, R##S.w, a##S.w, bb##S.w, rr##S.w);

    // 2-deep software pipeline over NJ=3 exact iterations
    {
        LOADG(0, A)
        LOADG(1, B)
        PROC(A)
        LOADG(2, C)
        PROC(B)
        PROC(C)
    }
#undef LOADG
#undef PIX1
#undef PROC

    #pragma unroll
    for (int o = 32; o > 0; o >>= 1) {
        as += __shfl_down(as, o);
        ac += __shfl_down(ac, o);
        ar += __shfl_down(ar, o);
    }
    __shared__ float sred[3][NTHR / 64];
    const int wv = threadIdx.x >> 6, lane = threadIdx.x & 63;
    if (lane == 0) { sred[0][wv] = as; sred[1][wv] = ac; sred[2][wv] = ar; }
    __syncthreads();
    if (threadIdx.x == 0) {
        float ts = 0.f, tc = 0.f, tr = 0.f;
        #pragma unroll
        for (int w = 0; w < NTHR / 64; ++w) { ts += sred[0][w]; tc += sred[1][w]; tr += sred[2][w]; }
        float* pp = partials + (size_t)(b * GXB + blockIdx.x) * 3;
        pp[0] = ts; pp[1] = tc; pp[2] = tr;
    }
}

// ---------- Finalize: deterministic reduce of 192 block-partials per image ----------
__global__ __launch_bounds__(NTHR) void finalize(
    const float* __restrict__ partials, float* __restrict__ out)
{
    const int b = blockIdx.x;
    float s = 0.f, c = 0.f, r = 0.f;
    if (threadIdx.x < GXB) {
        const float* pp = partials + (size_t)(b * GXB + threadIdx.x) * 3;
        s = pp[0]; c = pp[1]; r = pp[2];
    }
    #pragma unroll
    for (int o = 32; o > 0; o >>= 1) {
        s += __shfl_down(s, o);
        c += __shfl_down(c, o);
        r += __shfl_down(r, o);
    }
    __shared__ float sr[3][NTHR / 64];
    const int wv = threadIdx.x >> 6, lane = threadIdx.x & 63;
    if (lane == 0) { sr[0][wv] = s; sr[1][wv] = c; sr[2][wv] = r; }
    __syncthreads();
    if (threadIdx.x == 0) {
        float ts = 0.f, tc = 0.f, tr = 0.f;
        #pragma unroll
        for (int w = 0; w < NTHR / 64; ++w) { ts += sr[0][w]; tc += sr[1][w]; tr += sr[2][w]; }
        float tot = ts + tc + tr;
        out[     b] = tot;
        out[ 8 + b] = 0.f;
        out[16 + b] = tot;
        out[24 + b] = 0.f;
        out[32 + b] = ts;
        out[40 + b] = tc;
        out[48 + b] = tr;
        out[56 + b] = 0.f;
    }
}

extern "C" void kernel_launch(void* const* d_in, const int* in_sizes, int n_in,
                              void* d_out, int out_size, void* d_ws, size_t ws_size,
                              hipStream_t stream) {
    const float* pred = (const float*)d_in[0];
    const int*   inst = (const int*)d_in[1];
    // d_in[2] = label (unused by the reference)
    const float* gtR  = (const float*)d_in[3];
    const float* gts  = (const float*)d_in[4];
    const float* gtc  = (const float*)d_in[5];
    const float* gci  = (const float*)d_in[6];
    const int*   ign  = (const int*)d_in[7];
    float* out = (float*)d_out;

    int*    g_counts = (int*)d_ws;
    float*  partials = (float*)((char*)d_ws + 4096);                 // 8*192*3*4 = 18432 B
    uchar4* wbp      = (uchar4*)((char*)d_ws + 65536);               // 4.72 MB byte plane
    const size_t need_bytes = 65536 + (size_t)B_IMG * HW;
    const int use_bytes = (ws_size >= need_bytes) ? 1 : 0;

    hipMemsetAsync(g_counts, 0, B_IMG * MAXI * sizeof(int), stream);

    dim3 grid(GXB, B_IMG);
    pass1_count<<<grid, NTHR, 0, stream>>>(inst, ign, g_counts, wbp, use_bytes);
    if (use_bytes)
        pass2_loss<1><<<grid, NTHR, 0, stream>>>(pred, inst, ign, wbp, gtR, gts, gtc, gci, g_counts, partials);
    else
        pass2_loss<0><<<grid, NTHR, 0, stream>>>(pred, inst, ign, wbp, gtR, gts, gtc, gci, g_counts, partials);
    finalize<<<B_IMG, NTHR, 0, stream>>>(partials, out);
}